// Round 2
// baseline (244.088 us; speedup 1.0000x reference)
//
#include <hip/hip_runtime.h>
#include <math.h>

// RWKV WKV forward — single fused kernel, v2 (latency-oriented re-tile).
// B=8, T=2048, H=768. NC=64 chunks of L=32.
// Block = 64 chunks x 8 h = 512 threads; grid = (H/8, B) = (96, 8) = 768 blocks.
// -> uniform 3 blocks (24 waves) per CU on all 256 CUs, serial chains halved
//    vs v1 (32+32 steps instead of 64+64).
// Phase A: each thread builds its chunk's local (a,b,e) aggregate.
// Scan:    Hillis-Steele inclusive scan over 64 chunks in LDS (6 steps,
//          ping-pong). Uniform decay shift w*L*2^s per step is exact because
//          all chunks have identical length L.
// Phase C: each thread replays its chunk from the exclusive prefix.

#define B_  8
#define T_  2048
#define H_  768
#define NC_ 64
#define L_  32
#define HG_ 8                    // h-slice per block
#define NT_ (NC_ * HG_)         // 512 threads
#define SCAN_STEPS 6             // log2(NC_)

__global__ __launch_bounds__(NT_) void wkv_fused(
    const float* __restrict__ key, const float* __restrict__ val,
    const float* __restrict__ time_decay, const float* __restrict__ time_first,
    float* __restrict__ out)
{
    // ping-pong scan buffers: 2 * 3 * 64 * 8 * 4B = 12 KB LDS
    __shared__ float sa[2][NC_][HG_];
    __shared__ float sb[2][NC_][HG_];
    __shared__ float se[2][NC_][HG_];

    const int tid = threadIdx.x;
    const int c   = tid >> 3;          // chunk 0..63
    const int ho  = tid & 7;           // h within slice
    const int h   = blockIdx.x * HG_ + ho;
    const int b   = blockIdx.y;

    const float w = -__expf(time_decay[h]);
    const float u = time_first[h];

    const size_t base = ((size_t)b * T_ + (size_t)c * L_) * H_ + h;
    const float* kp = key + base;
    const float* vp = val + base;

    // ---------------- Phase A: local chunk aggregate ----------------
    // Invariant: true A = a * e^e, true B = bb * e^e.
    float a = 0.f, bb = 0.f, e = -INFINITY;
#pragma unroll 8
    for (int t = 0; t < L_; ++t) {
        const float kt = kp[(size_t)t * H_];
        const float vt = vp[(size_t)t * H_];
        const float ew = e + w;
        const float m2 = fmaxf(ew, kt);
        const float s1 = __expf(ew - m2);
        const float s2 = __expf(kt - m2);
        a  = fmaf(s1, a,  s2 * vt);
        bb = fmaf(s1, bb, s2);
        e  = m2;
    }

    int cur = 0;
    sa[cur][c][ho] = a; sb[cur][c][ho] = bb; se[cur][c][ho] = e;
    __syncthreads();

    // ---------------- Inclusive Hillis-Steele scan over chunks ----------------
    // combine(prefix_earlier, segment_later):
    //   earlier exponent shifted by decay of the later segment: wL * 2^s
    const float wL = w * (float)L_;
#pragma unroll
    for (int s = 0; s < SCAN_STEPS; ++s) {
        const int d = 1 << s;
        float na = sa[cur][c][ho];
        float nb = sb[cur][c][ho];
        float ne = se[cur][c][ho];
        if (c >= d) {
            const float pa = sa[cur][c - d][ho];
            const float pb = sb[cur][c - d][ho];
            const float pe = se[cur][c - d][ho] + wL * (float)d;
            const float m  = fmaxf(pe, ne);
            const float x  = __expf(pe - m);
            const float y  = __expf(ne - m);
            na = fmaf(pa, x, na * y);
            nb = fmaf(pb, x, nb * y);
            ne = m;
        }
        sa[cur ^ 1][c][ho] = na;
        sb[cur ^ 1][c][ho] = nb;
        se[cur ^ 1][c][ho] = ne;
        __syncthreads();
        cur ^= 1;
    }

    // exclusive prefix = incoming state for chunk c
    float ra = 0.f, rb = 0.f, re = -INFINITY;
    if (c > 0) {
        ra = sa[cur][c - 1][ho];
        rb = sb[cur][c - 1][ho];
        re = se[cur][c - 1][ho];
    }

    // ---------------- Phase C: replay chunk, emit outputs ----------------
    float* op = out + base;
#pragma unroll 8
    for (int t = 0; t < L_; ++t) {
        const float kt = kp[(size_t)t * H_];
        const float vt = vp[(size_t)t * H_];

        // output at this timestep (state BEFORE update)
        const float uk = u + kt;
        const float m1 = fmaxf(re, uk);
        const float wt = __expf(uk - m1);
        const float sc = __expf(re - m1);
        const float num = fmaf(ra, sc, wt * vt);
        const float den = fmaf(rb, sc, wt);
        op[(size_t)t * H_] = __fdividef(num, den);

        // state update
        const float ew = re + w;
        const float m2 = fmaxf(ew, kt);
        const float s1 = __expf(ew - m2);
        const float s2 = __expf(kt - m2);
        ra = fmaf(s1, ra, s2 * vt);
        rb = fmaf(s1, rb, s2);
        re = m2;
    }
}

extern "C" void kernel_launch(void* const* d_in, const int* in_sizes, int n_in,
                              void* d_out, int out_size, void* d_ws, size_t ws_size,
                              hipStream_t stream) {
    const float* key = (const float*)d_in[0];
    const float* val = (const float*)d_in[1];
    const float* td  = (const float*)d_in[2];
    const float* tf  = (const float*)d_in[3];
    float* out = (float*)d_out;

    dim3 grid(H_ / HG_, B_);   // 96 x 8 = 768 blocks, 512 threads each
    wkv_fused<<<grid, NT_, 0, stream>>>(key, val, td, tf, out);
}

// Round 5
// 178.508 us; speedup vs baseline: 1.3674x; 1.3674x over previous
//
#include <hip/hip_runtime.h>
#include <math.h>

// RWKV WKV forward — single fused kernel, v5 (v3 thesis, de-risked launch).
// B=8, T=2048, H=768. NC=64 chunks of L=32.
// Thread = (chunk c, float4 h-group): 64 c x 8 groups = 512 threads.
// Block spans 32 h = one full 128B line -> no over-fetch (v2's 4x bug).
// 4 independent recurrence chains per thread (ILP x4) + 16B/lane loads.
// Grid = (H/32, B) = (24, 8) = 192 blocks of 8 waves.
// NOTE: v3/v4 failed to run; common suspect was __launch_bounds__(1024,4)
// (hard VGPR bound). This version: 512 threads (proven in round 2), plain
// __launch_bounds__(512), 25.3 KB LDS single-buffer scan.
// Scan: depth-6 Hillis-Steele over chunks, read/barrier/write/barrier.
// Pad 33 -> bank (c+col) mod 32, exact 2-way (free).

#define B_   8
#define T_   2048
#define H_   768
#define H4_  (H_/4)          // 192 float4 per row
#define NC_  64
#define L_   32
#define HO4_ 8               // float4 h-groups per block (32 h)
#define NT_  512
#define PAD_ 33
#define SCAN_STEPS 6

__global__ __launch_bounds__(NT_) void wkv_fused(
    const float* __restrict__ key, const float* __restrict__ val,
    const float* __restrict__ time_decay, const float* __restrict__ time_first,
    float* __restrict__ out)
{
    __shared__ float sa[NC_][PAD_];   // 3 * 64*33*4B = 25.3 KB total
    __shared__ float sb[NC_][PAD_];
    __shared__ float se[NC_][PAD_];

    const int tid = threadIdx.x;
    const int ho4 = tid & (HO4_ - 1);    // 0..7
    const int c   = tid >> 3;            // 0..63
    const int h0  = blockIdx.x * (HO4_ * 4) + ho4 * 4;
    const int b   = blockIdx.y;
    const int col = ho4 * 4;

    const float4 td4 = *(const float4*)(time_decay + h0);
    const float4 tf4 = *(const float4*)(time_first + h0);
    float w[4], u[4];
    w[0] = -__expf(td4.x); w[1] = -__expf(td4.y);
    w[2] = -__expf(td4.z); w[3] = -__expf(td4.w);
    u[0] = tf4.x; u[1] = tf4.y; u[2] = tf4.z; u[3] = tf4.w;

    const size_t base = ((size_t)b * T_ + (size_t)c * L_) * H_ + h0;
    const float4* kp = (const float4*)(key + base);
    const float4* vp = (const float4*)(val + base);

    // ---------------- Phase A: local chunk aggregate (4 channels) --------------
    // Invariant: true A = a * e^e, true B = bb * e^e.
    float a[4]  = {0.f, 0.f, 0.f, 0.f};
    float bb[4] = {0.f, 0.f, 0.f, 0.f};
    float e[4]  = {-INFINITY, -INFINITY, -INFINITY, -INFINITY};

#pragma unroll 4
    for (int t = 0; t < L_; ++t) {
        const float4 k4 = kp[(size_t)t * H4_];
        const float4 v4 = vp[(size_t)t * H4_];
        const float kt[4] = {k4.x, k4.y, k4.z, k4.w};
        const float vt[4] = {v4.x, v4.y, v4.z, v4.w};
#pragma unroll
        for (int j = 0; j < 4; ++j) {
            const float ew = e[j] + w[j];
            const float m2 = fmaxf(ew, kt[j]);
            const float s1 = __expf(ew - m2);
            const float s2 = __expf(kt[j] - m2);
            a[j]  = fmaf(s1, a[j],  s2 * vt[j]);
            bb[j] = fmaf(s1, bb[j], s2);
            e[j]  = m2;
        }
    }

    // ---------------- Inclusive scan over 64 chunks (single LDS buffer) --------
#pragma unroll
    for (int j = 0; j < 4; ++j) {
        sa[c][col + j] = a[j];
        sb[c][col + j] = bb[j];
        se[c][col + j] = e[j];
    }
    __syncthreads();

#pragma unroll
    for (int s = 0; s < SCAN_STEPS; ++s) {
        const int d = 1 << s;
        const bool act = (c >= d);
        float pa[4], pb[4], pe[4];
        if (act) {
#pragma unroll
            for (int j = 0; j < 4; ++j) {
                pa[j] = sa[c - d][col + j];
                pb[j] = sb[c - d][col + j];
                pe[j] = se[c - d][col + j] + w[j] * (float)(L_ * d);
            }
        }
        __syncthreads();   // all step-s reads done before overwrites
        if (act) {
#pragma unroll
            for (int j = 0; j < 4; ++j) {
                const float m = fmaxf(pe[j], e[j]);
                const float x = __expf(pe[j] - m);
                const float y = __expf(e[j] - m);
                a[j]  = fmaf(pa[j], x, a[j] * y);
                bb[j] = fmaf(pb[j], x, bb[j] * y);
                e[j]  = m;
                sa[c][col + j] = a[j];
                sb[c][col + j] = bb[j];
                se[c][col + j] = e[j];
            }
        }
        __syncthreads();   // step-s writes visible before step-s+1 reads
    }

    // exclusive prefix = incoming state for chunk c
    float ra[4] = {0.f, 0.f, 0.f, 0.f};
    float rb[4] = {0.f, 0.f, 0.f, 0.f};
    float re[4] = {-INFINITY, -INFINITY, -INFINITY, -INFINITY};
    if (c > 0) {
#pragma unroll
        for (int j = 0; j < 4; ++j) {
            ra[j] = sa[c - 1][col + j];
            rb[j] = sb[c - 1][col + j];
            re[j] = se[c - 1][col + j];
        }
    }

    // ---------------- Phase C: replay chunk, emit outputs ----------------------
    float4* op = (float4*)(out + base);
#pragma unroll 4
    for (int t = 0; t < L_; ++t) {
        const float4 k4 = kp[(size_t)t * H4_];
        const float4 v4 = vp[(size_t)t * H4_];
        const float kt[4] = {k4.x, k4.y, k4.z, k4.w};
        const float vt[4] = {v4.x, v4.y, v4.z, v4.w};
        float o[4];
#pragma unroll
        for (int j = 0; j < 4; ++j) {
            // output at this timestep (state BEFORE update)
            const float uk = u[j] + kt[j];
            const float m1 = fmaxf(re[j], uk);
            const float wt = __expf(uk - m1);
            const float sc = __expf(re[j] - m1);
            const float num = fmaf(ra[j], sc, wt * vt[j]);
            const float den = fmaf(rb[j], sc, wt);
            o[j] = __fdividef(num, den);

            // state update
            const float ew = re[j] + w[j];
            const float m2 = fmaxf(ew, kt[j]);
            const float s1 = __expf(ew - m2);
            const float s2 = __expf(kt[j] - m2);
            ra[j] = fmaf(s1, ra[j], s2 * vt[j]);
            rb[j] = fmaf(s1, rb[j], s2);
            re[j] = m2;
        }
        float4 o4;
        o4.x = o[0]; o4.y = o[1]; o4.z = o[2]; o4.w = o[3];
        op[(size_t)t * H4_] = o4;
    }
}

extern "C" void kernel_launch(void* const* d_in, const int* in_sizes, int n_in,
                              void* d_out, int out_size, void* d_ws, size_t ws_size,
                              hipStream_t stream) {
    const float* key = (const float*)d_in[0];
    const float* val = (const float*)d_in[1];
    const float* td  = (const float*)d_in[2];
    const float* tf  = (const float*)d_in[3];
    float* out = (float*)d_out;

    dim3 grid(H_ / (HO4_ * 4), B_);   // (24, 8) = 192 blocks, 512 threads each
    wkv_fused<<<grid, NT_, 0, stream>>>(key, val, td, tf, out);
}

// Round 6
// 163.509 us; speedup vs baseline: 1.4928x; 1.0917x over previous
//
#include <hip/hip_runtime.h>
#include <math.h>

// RWKV WKV forward — v6: two plain kernels over T-quarters (no serial phase,
// no cooperative launch, no >256-thread blocks — maximally boring launch).
// B=8, T=2048, H=768. T split into NQ=4 quarters of 512; each quarter has
// NCB=32 chunks of L=16.
// Block = (h-slice of 32h, quarter q, batch b): 32 chunks x 8 float4-groups
// = 256 threads. Grid = (24, 4, 8) = 768 blocks = 12 waves/CU on ALL 256 CUs
// (fixes v1/v5's 192-block imbalance). Blocks span 32h = full 128B lines
// (fixes v2's 4x over-fetch). float4 loads, 4 independent chains/thread.
// k1: chunk aggregates + depth-5 LDS scan; store per-chunk local exclusive
//     prefixes + per-quarter totals to d_ws (9.7 MB).
// k2: incoming = fold(totals q'<q, shifted by w*512 each) ⊕ local exclusive
//     (shifted by w*16*c), then replay 16 steps and write out. k,v re-read
//     is L3-resident (100 MB < 256 MB L3).

#define B_    8
#define T_    2048
#define H_    768
#define H4_   (H_/4)          // 192
#define NQ_   4
#define NCB_  32              // chunks per block
#define L_    16
#define QLEN_ (NCB_*L_)       // 512
#define HS_   (H_/32)         // 24 h-slices
#define HO4_  8
#define NT_   256
#define PAD_  33

#define EXCL_N ((size_t)B_*HS_*NQ_*NCB_*32)   // 786432 floats per array
#define TOT_N  ((size_t)B_*HS_*NQ_*32)        // 24576 floats per array

// ---------------- k1: aggregates + block scan + store prefixes ----------------
__global__ __launch_bounds__(NT_) void wkv_p1(
    const float* __restrict__ key, const float* __restrict__ val,
    const float* __restrict__ time_decay,
    float* __restrict__ ea, float* __restrict__ eb, float* __restrict__ ee,
    float* __restrict__ ta, float* __restrict__ tb, float* __restrict__ te)
{
    __shared__ float sa[NCB_][PAD_];   // 3 * 32*33*4B = 12.7 KB
    __shared__ float sb[NCB_][PAD_];
    __shared__ float se[NCB_][PAD_];

    const int tid = threadIdx.x;
    const int ho4 = tid & (HO4_ - 1);
    const int c   = tid >> 3;          // 0..31 local chunk
    const int col = ho4 * 4;
    const int hs  = blockIdx.x;
    const int q   = blockIdx.y;
    const int b   = blockIdx.z;
    const int h0  = hs * 32 + col;

    const float4 td4 = *(const float4*)(time_decay + h0);
    float w[4];
    w[0] = -__expf(td4.x); w[1] = -__expf(td4.y);
    w[2] = -__expf(td4.z); w[3] = -__expf(td4.w);

    const int cg = q * NCB_ + c;
    const size_t base = ((size_t)b * T_ + (size_t)cg * L_) * H_ + h0;
    const float4* kp = (const float4*)(key + base);
    const float4* vp = (const float4*)(val + base);

    float a[4]  = {0.f, 0.f, 0.f, 0.f};
    float bb[4] = {0.f, 0.f, 0.f, 0.f};
    float e[4]  = {-INFINITY, -INFINITY, -INFINITY, -INFINITY};

#pragma unroll 4
    for (int t = 0; t < L_; ++t) {
        const float4 k4 = kp[(size_t)t * H4_];
        const float4 v4 = vp[(size_t)t * H4_];
        const float kt[4] = {k4.x, k4.y, k4.z, k4.w};
        const float vt[4] = {v4.x, v4.y, v4.z, v4.w};
#pragma unroll
        for (int j = 0; j < 4; ++j) {
            const float ew = e[j] + w[j];
            const float m2 = fmaxf(ew, kt[j]);
            const float s1 = __expf(ew - m2);
            const float s2 = __expf(kt[j] - m2);
            a[j]  = fmaf(s1, a[j],  s2 * vt[j]);
            bb[j] = fmaf(s1, bb[j], s2);
            e[j]  = m2;
        }
    }

    // depth-5 inclusive scan over the block's 32 chunks (single LDS buffer)
#pragma unroll
    for (int j = 0; j < 4; ++j) {
        sa[c][col + j] = a[j];
        sb[c][col + j] = bb[j];
        se[c][col + j] = e[j];
    }
    __syncthreads();

#pragma unroll
    for (int s = 0; s < 5; ++s) {
        const int d = 1 << s;
        const bool act = (c >= d);
        float pa[4], pb[4], pe[4];
        if (act) {
#pragma unroll
            for (int j = 0; j < 4; ++j) {
                pa[j] = sa[c - d][col + j];
                pb[j] = sb[c - d][col + j];
                pe[j] = se[c - d][col + j] + w[j] * (float)(L_ * d);
            }
        }
        __syncthreads();
        if (act) {
#pragma unroll
            for (int j = 0; j < 4; ++j) {
                const float m = fmaxf(pe[j], e[j]);
                const float x = __expf(pe[j] - m);
                const float y = __expf(e[j] - m);
                a[j]  = fmaf(pa[j], x, a[j] * y);
                bb[j] = fmaf(pb[j], x, bb[j] * y);
                e[j]  = m;
                sa[c][col + j] = a[j];
                sb[c][col + j] = bb[j];
                se[c][col + j] = e[j];
            }
        }
        __syncthreads();
    }

    // local exclusive prefix (identity for c==0)
    float xa[4] = {0.f, 0.f, 0.f, 0.f};
    float xb[4] = {0.f, 0.f, 0.f, 0.f};
    float xe[4] = {-INFINITY, -INFINITY, -INFINITY, -INFINITY};
    if (c > 0) {
#pragma unroll
        for (int j = 0; j < 4; ++j) {
            xa[j] = sa[c - 1][col + j];
            xb[j] = sb[c - 1][col + j];
            xe[j] = se[c - 1][col + j];
        }
    }

    const size_t eoff = ((((size_t)b * HS_ + hs) * NQ_ + q) * NCB_ + c) * 32 + col;
#pragma unroll
    for (int j = 0; j < 4; ++j) {
        ea[eoff + j] = xa[j];
        eb[eoff + j] = xb[j];
        ee[eoff + j] = xe[j];
    }
    if (c == NCB_ - 1) {   // registers hold the inclusive total of the quarter
        const size_t toff = (((size_t)b * HS_ + hs) * NQ_ + q) * 32 + col;
#pragma unroll
        for (int j = 0; j < 4; ++j) {
            ta[toff + j] = a[j];
            tb[toff + j] = bb[j];
            te[toff + j] = e[j];
        }
    }
}

// ---------------- k2: fold prefixes + replay + emit --------------------------
__global__ __launch_bounds__(NT_) void wkv_p2(
    const float* __restrict__ key, const float* __restrict__ val,
    const float* __restrict__ time_decay, const float* __restrict__ time_first,
    const float* __restrict__ ea, const float* __restrict__ eb,
    const float* __restrict__ ee,
    const float* __restrict__ ta, const float* __restrict__ tb,
    const float* __restrict__ te,
    float* __restrict__ out)
{
    const int tid = threadIdx.x;
    const int ho4 = tid & (HO4_ - 1);
    const int c   = tid >> 3;
    const int col = ho4 * 4;
    const int hs  = blockIdx.x;
    const int q   = blockIdx.y;
    const int b   = blockIdx.z;
    const int h0  = hs * 32 + col;

    const float4 td4 = *(const float4*)(time_decay + h0);
    const float4 tf4 = *(const float4*)(time_first + h0);
    float w[4], u[4];
    w[0] = -__expf(td4.x); w[1] = -__expf(td4.y);
    w[2] = -__expf(td4.z); w[3] = -__expf(td4.w);
    u[0] = tf4.x; u[1] = tf4.y; u[2] = tf4.z; u[3] = tf4.w;

    // own local exclusive prefix
    const size_t eoff = ((((size_t)b * HS_ + hs) * NQ_ + q) * NCB_ + c) * 32 + col;
    float ra[4], rb[4], re[4];
#pragma unroll
    for (int j = 0; j < 4; ++j) {
        ra[j] = ea[eoff + j];
        rb[j] = eb[eoff + j];
        re[j] = ee[eoff + j];
    }

    // fold quarter totals q' = 0..q-1 (uniform per block; at most 3 folds)
    float pa[4] = {0.f, 0.f, 0.f, 0.f};
    float pb[4] = {0.f, 0.f, 0.f, 0.f};
    float pe[4] = {-INFINITY, -INFINITY, -INFINITY, -INFINITY};
    for (int qq = 0; qq < q; ++qq) {
        const size_t toff = (((size_t)b * HS_ + hs) * NQ_ + qq) * 32 + col;
#pragma unroll
        for (int j = 0; j < 4; ++j) {
            const float Ta = ta[toff + j];
            const float Tb = tb[toff + j];
            const float Te = te[toff + j];
            const float sh = pe[j] + w[j] * (float)QLEN_;  // -inf stays -inf
            const float m  = fmaxf(sh, Te);                // finite (Te finite)
            const float x  = __expf(sh - m);
            const float y  = __expf(Te - m);
            pa[j] = fmaf(pa[j], x, Ta * y);
            pb[j] = fmaf(pb[j], x, Tb * y);
            pe[j] = m;
        }
    }

    // incoming state = combine(P, local exclusive, len = c*L_)
#pragma unroll
    for (int j = 0; j < 4; ++j) {
        const float sh = pe[j] + w[j] * (float)(c * L_);
        const float m  = fmaxf(sh, re[j]);
        if (m > -INFINITY) {           // guard -inf minus -inf (q==0 && c==0)
            const float x = __expf(sh - m);
            const float y = __expf(re[j] - m);
            ra[j] = fmaf(pa[j], x, ra[j] * y);
            rb[j] = fmaf(pb[j], x, rb[j] * y);
            re[j] = m;
        }
    }

    const int cg = q * NCB_ + c;
    const size_t base = ((size_t)b * T_ + (size_t)cg * L_) * H_ + h0;
    const float4* kp = (const float4*)(key + base);
    const float4* vp = (const float4*)(val + base);
    float4*       op = (float4*)(out + base);

#pragma unroll 4
    for (int t = 0; t < L_; ++t) {
        const float4 k4 = kp[(size_t)t * H4_];
        const float4 v4 = vp[(size_t)t * H4_];
        const float kt[4] = {k4.x, k4.y, k4.z, k4.w};
        const float vt[4] = {v4.x, v4.y, v4.z, v4.w};
        float o[4];
#pragma unroll
        for (int j = 0; j < 4; ++j) {
            // output at this timestep (state BEFORE update)
            const float uk = u[j] + kt[j];
            const float m1 = fmaxf(re[j], uk);
            const float wt = __expf(uk - m1);
            const float sc = __expf(re[j] - m1);
            const float num = fmaf(ra[j], sc, wt * vt[j]);
            const float den = fmaf(rb[j], sc, wt);
            o[j] = __fdividef(num, den);

            // state update
            const float ew = re[j] + w[j];
            const float m2 = fmaxf(ew, kt[j]);
            const float s1 = __expf(ew - m2);
            const float s2 = __expf(kt[j] - m2);
            ra[j] = fmaf(s1, ra[j], s2 * vt[j]);
            rb[j] = fmaf(s1, rb[j], s2);
            re[j] = m2;
        }
        float4 o4;
        o4.x = o[0]; o4.y = o[1]; o4.z = o[2]; o4.w = o[3];
        op[(size_t)t * H4_] = o4;
    }
}

extern "C" void kernel_launch(void* const* d_in, const int* in_sizes, int n_in,
                              void* d_out, int out_size, void* d_ws, size_t ws_size,
                              hipStream_t stream) {
    const float* key = (const float*)d_in[0];
    const float* val = (const float*)d_in[1];
    const float* td  = (const float*)d_in[2];
    const float* tf  = (const float*)d_in[3];
    float* out = (float*)d_out;

    float* ea = (float*)d_ws;
    float* eb = ea + EXCL_N;
    float* ee = eb + EXCL_N;
    float* ta = ee + EXCL_N;
    float* tb = ta + TOT_N;
    float* te = tb + TOT_N;   // total: 3*786432 + 3*24576 floats = 9.7 MB

    dim3 grid(HS_, NQ_, B_);  // (24, 4, 8) = 768 blocks, 256 threads each
    wkv_p1<<<grid, NT_, 0, stream>>>(key, val, td, ea, eb, ee, ta, tb, te);
    wkv_p2<<<grid, NT_, 0, stream>>>(key, val, td, tf, ea, eb, ee, ta, tb, te, out);
}